// Round 17
// baseline (92.086 us; speedup 1.0000x reference)
//
#include <hip/hip_runtime.h>

#define NF 160
#define NP 80
#define ND 64
#define NC 512
#define NV 81                  // stored v columns 0..80 (Hermitian half)
#define NPIXH (NF*NV)          // 12960
#define NPIXP 13056            // padded: 1632*8
#define NSTR 1632              // pixel stripes (grid.x of k_cand)
#define STRIPE 8               // pixels per stripe
#define RECQ 21                // float4 planes per pixel record (LDS-only)
#define BT 128                 // k_cand block threads
#define CPT 4                  // candidates per thread (128*4 = 512 = NC)
#define VG 9                   // v-columns per fft block (81 = 9*9)
#define TWO_PI 6.283185307179586f

// per-pixel precomputed parameter slots (for k_amin_ifftu)
#define IP_AR 0
#define IP_AI 1
#define IP_BR 2
#define IP_BI 3
#define IP_P  4
#define IP_Q  5
#define IP_R  6
#define IP_C2T 7
#define IP_S2T 8
#define IP_K  9
#define NPRM 10

__device__ __forceinline__ void rot(float& c, float& s, float stc, float sts) {
  float t1 = s * sts;
  float t2 = s * stc;
  float cn = fmaf(c, stc, -t1);
  s = fmaf(c, sts, t2);
  c = cn;
}

__device__ __forceinline__ void start_i_pow(int n, float& c, float& s) {
  switch (n & 3) {
    case 0: c = 1.f; s = 0.f; break;
    case 1: c = 0.f; s = 1.f; break;
    case 2: c = -1.f; s = 0.f; break;
    default: c = 0.f; s = -1.f; break;
  }
}

// K1: fused 2D DFT. Block = (d, v-group of 9). Phase 1: T[a][vl] tile in LDS
// (row DFT over b). Phase 2: column DFT over a from LDS -> Y[d][u][v].
// Zero redundancy; T never touches global memory.
__global__ __launch_bounds__(256) void k_fft_xy(const float* __restrict__ patch,
                                                const float* __restrict__ gw,
                                                float2* __restrict__ Y) {
  __shared__ float2 Tl[NP][VG];               // 80*9*8 = 5760 B
  int d = blockIdx.x / 9;                     // 0..63
  int v0 = (blockIdx.x % 9) * VG;             // 0,9,...,72
  int t = threadIdx.x;
  // phase 1: 720 items (a, vl)
  for (int it = t; it < NP * VG; it += 256) {
    int a = it / VG;
    int vl = it - a * VG;
    int v = v0 + vl;
    float c, s;
    start_i_pow(v, c, s);
    float stc, sts;
    sincosf(-TWO_PI * (float)v / (float)NF, &sts, &stc);
    const float* prow = patch + (size_t)(d * NP + a) * NP;
    const float* grow = gw + a * NP;
    float accR = 0.f, accI = 0.f;
#pragma unroll 4
    for (int b = 0; b < NP; ++b) {
      float f = prow[b] * grow[b];
      accR = fmaf(f, c, accR);
      accI = fmaf(f, s, accI);
      rot(c, s, stc, sts);
    }
    Tl[a][vl] = make_float2(accR, accI);
  }
  __syncthreads();
  // phase 2: 1440 items (u, vl)
  for (int it = t; it < NF * VG; it += 256) {
    int u = it / VG;
    int vl = it - u * VG;
    float c, s;
    start_i_pow(u, c, s);
    float stc, sts;
    sincosf(-TWO_PI * (float)u / (float)NF, &sts, &stc);
    float accR = 0.f, accI = 0.f;
#pragma unroll 4
    for (int a = 0; a < NP; ++a) {
      float2 tt = Tl[a][vl];
      accR = fmaf(tt.x, c, accR);
      accR = fmaf(-tt.y, s, accR);
      accI = fmaf(tt.x, s, accI);
      accI = fmaf(tt.y, c, accI);
      rot(c, s, stc, sts);
    }
    Y[((size_t)d * NF + u) * NV + v0 + vl] = make_float2(accR, accI);
  }
}

// K2: fused prep+cand (R16-identical). Block owns an exclusive 8-pixel stripe.
__global__ __launch_bounds__(BT) void k_cand(const float2* __restrict__ Y,
                                             const float* __restrict__ delays,
                                             const float* __restrict__ kloss,
                                             const float* __restrict__ theta,
                                             const float* __restrict__ cand,
                                             float* __restrict__ partial,
                                             float* __restrict__ prm) {
  __shared__ float4 buf[STRIPE][RECQ];        // 2688 B record
  __shared__ float ykl[STRIPE][65];           // 2080 B (padded)
  int t = threadIdx.x;
  int p0 = blockIdx.x * STRIPE;               // 1632*8 = 13056 exactly

  // ---- prep phase ----
  {
    int px = t >> 4;                          // 0..7
    int dg = t & 15;                          // 0..15
    int p = p0 + px;
    bool valid = p < NPIXH;
    float k = 0.f, c2t = 0.f, s2t = 0.f, wgt = 0.f;
    int u = 0, v = 0;
    if (valid) {
      u = p / NV; v = p - u * NV;
      k = kloss[u * NF + v];
      float th = theta[((u + 80) % NF) * NF + ((v + 80) % NF)];
      c2t = cosf(2.f * th); s2t = sinf(2.f * th);
      if (v == 0 || v == 80) {
        if (u == 0 || u == 80) wgt = 1.f;
        else if (u < 80) wgt = 2.f;
        else wgt = 0.f;
      } else wgt = 2.f;
    }
    float mAr = 0.f, mAi = 0.f, mBr = 0.f, mBi = 0.f;
    float mP = 0.f, mQ = 0.f, mR = 0.f, mS = 0.f;
    float cd0t = 1.f, sd0t = 0.f, cd1t = 1.f, sd1t = 0.f;
#pragma unroll
    for (int j = 0; j < 4; ++j) {
      int d = dg * 4 + j;
      float sd, cd;
      sincosf(k * delays[d], &sd, &cd);
      float yx = 0.f, yy = 0.f;
      if (valid) {
        float2 y = Y[((size_t)d * NF + u) * NV + v];
        yx = y.x; yy = y.y;
      }
      mAr = fmaf(yx, cd, mAr);  mAi = fmaf(yy, cd, mAi);
      mBr = fmaf(yx, sd, mBr);  mBi = fmaf(yy, sd, mBi);
      mP = fmaf(cd, cd, mP);  mQ = fmaf(cd, sd, mQ);  mR = fmaf(sd, sd, mR);
      float yk = sqrtf(fmaf(yx, yx, yy * yy)) * k;
      ykl[px][d] = yk;
      mS = fmaf(yk, yk, mS);
      if (j == 0) { cd0t = cd; sd0t = sd; }
      if (j == 1) { cd1t = cd; sd1t = sd; }
    }
#pragma unroll
    for (int off = 8; off > 0; off >>= 1) {
      mAr += __shfl_xor(mAr, off);
      mAi += __shfl_xor(mAi, off);
      mBr += __shfl_xor(mBr, off);
      mBi += __shfl_xor(mBi, off);
      mP += __shfl_xor(mP, off);
      mQ += __shfl_xor(mQ, off);
      mR += __shfl_xor(mR, off);
      mS += __shfl_xor(mS, off);
    }
    if (dg == 0) {
      if (valid) {
        float tcd = 2.f * cosf(k * (delays[1] - delays[0]));
        buf[px][16] = make_float4(mAr, mAi, mBr, mBi);
        buf[px][17] = make_float4(mP, mQ, mR, mS);
        buf[px][18] = make_float4(c2t, s2t, k, wgt);
        buf[px][19] = make_float4(cd0t, sd0t, cd1t, sd1t);
        buf[px][20] = make_float4(tcd, 0.f, 0.f, 0.f);
        prm[IP_AR * NPIXP + p] = mAr;  prm[IP_AI * NPIXP + p] = mAi;
        prm[IP_BR * NPIXP + p] = mBr;  prm[IP_BI * NPIXP + p] = mBi;
        prm[IP_P * NPIXP + p] = mP;    prm[IP_Q * NPIXP + p] = mQ;
        prm[IP_R * NPIXP + p] = mR;    prm[IP_C2T * NPIXP + p] = c2t;
        prm[IP_S2T * NPIXP + p] = s2t; prm[IP_K * NPIXP + p] = k;
      } else {
        buf[px][16] = make_float4(0.f, 0.f, 0.f, 0.f);
        buf[px][17] = make_float4(1.f, 0.f, 1.f, 0.f);
        buf[px][18] = make_float4(0.f, 0.f, 0.f, 0.f);
        buf[px][19] = make_float4(1.f, 0.f, 1.f, 0.f);
        buf[px][20] = make_float4(2.f, 0.f, 0.f, 0.f);
      }
    }
    int px2 = t >> 4, jj = t & 15;
    buf[px2][jj] = make_float4(ykl[px2][2 * jj], ykl[px2][63 - 2 * jj],
                               ykl[px2][2 * jj + 1], ykl[px2][62 - 2 * jj]);
  }
  __syncthreads();

  // ---- candidate phase ----
  float dc[CPT], xx[CPT], yy[CPT], acc[CPT];
#pragma unroll
  for (int ci = 0; ci < CPT; ++ci) {
    int c = t + ci * BT;
    dc[ci] = cand[c * 3 + 0];
    xx[ci] = cand[c * 3 + 1];
    yy[ci] = cand[c * 3 + 2];
    acc[ci] = 0.f;
  }
#pragma unroll
  for (int i = 0; i < STRIPE; ++i) {
    const float4* r = &buf[i][0];
    float4 pA = r[16];                        // Ar,Ai,Br,Bi
    float4 pB = r[17];                        // Pm,Qm,Rm,S0
    float4 pC = r[18];                        // c2t,s2t,k,wgt
    float4 pD = r[19];                        // cd0,sd0,cd1,sd1
    float tcd = r[20].x;
    float4 y0 = r[0];
    float A0[CPT], A1[CPT], B0[CPT], B1[CPT], M[CPT], F0[CPT], F1[CPT];
#pragma unroll
    for (int ci = 0; ci < CPT; ++ci) {
      float w_ = fmaf(xx[ci], pC.x, fmaf(yy[ci], pC.y, dc[ci]));
      float sw, cw;
      __sincosf(pC.z * w_, &sw, &cw);
      float rr = fmaf(cw, pA.x, sw * pA.z);
      float ri = fmaf(cw, pA.y, sw * pA.w);
      float lhs = fmaf(cw * cw, pB.x, fmaf(2.f * cw * sw, pB.y, sw * sw * pB.z));
      float rabs = __builtin_amdgcn_sqrtf(fmaf(rr, rr, ri * ri));
      float rl = __builtin_amdgcn_rcpf(lhs);
      float e = fmaf(-lhs, rl, 1.f);
      rl = fmaf(rl, e, rl);                   // refined 1/lhs
      float kX = pC.z * rabs * rl;
      F0[ci] = fmaf(kX * kX, lhs, pB.w);      // contrib = F0 + F1*M
      F1[ci] = -2.f * kX;
      float t0 = pD.x * cw, u0 = pD.y * sw;
      float t1 = pD.z * cw, u1 = pD.w * sw;
      A0[ci] = t0 + u0;  B0[ci] = t0 - u0;    // cos(k d0 -/+ kw)
      A1[ci] = t1 + u1;  B1[ci] = t1 - u1;    // cos(k d1 -/+ kw)
      float m = y0.x * fabsf(A0[ci]);
      m = fmaf(y0.y, fabsf(B0[ci]), m);
      m = fmaf(y0.z, fabsf(A1[ci]), m);
      m = fmaf(y0.w, fabsf(B1[ci]), m);
      M[ci] = m;
    }
    float4 ykn = r[1];
#pragma unroll
    for (int jj = 1; jj < 16; ++jj) {
      float4 yk = ykn;
      if (jj < 15) ykn = r[jj + 1];           // 1-ahead prefetch
#pragma unroll
      for (int ci = 0; ci < CPT; ++ci) {
        float An = fmaf(tcd, A1[ci], -A0[ci]);
        float Bn = fmaf(tcd, B1[ci], -B0[ci]);
        float m = fmaf(yk.x, fabsf(An), M[ci]);
        m = fmaf(yk.y, fabsf(Bn), m);
        float An2 = fmaf(tcd, An, -A1[ci]);
        float Bn2 = fmaf(tcd, Bn, -B1[ci]);
        m = fmaf(yk.z, fabsf(An2), m);
        m = fmaf(yk.w, fabsf(Bn2), m);
        M[ci] = m;
        A0[ci] = An; A1[ci] = An2;
        B0[ci] = Bn; B1[ci] = Bn2;
      }
    }
#pragma unroll
    for (int ci = 0; ci < CPT; ++ci)
      acc[ci] = fmaf(fmaf(F1[ci], M[ci], F0[ci]), pC.w, acc[ci]);
  }
#pragma unroll
  for (int ci = 0; ci < CPT; ++ci)
    partial[(size_t)blockIdx.x * NC + t + ci * BT] = acc[ci];
}

// K3: loss[c] = sum over stripes — one block per candidate, parallel loads,
// deterministic LDS tree reduction.
__global__ __launch_bounds__(256) void k_sum(const float* __restrict__ partial,
                                             float* __restrict__ loss) {
  __shared__ float red[256];
  int c = blockIdx.x;                         // 512 blocks
  float s = 0.f;
  for (int j = threadIdx.x; j < NSTR; j += 256)
    s += partial[(size_t)j * NC + c];
  red[threadIdx.x] = s;
  __syncthreads();
  for (int off = 128; off > 0; off >>= 1) {
    if (threadIdx.x < off) red[threadIdx.x] += red[threadIdx.x + off];
    __syncthreads();
  }
  if (threadIdx.x == 0) loss[c] = red[0];
}

// K4: fused redundant argmin (per block) + ifft_u row DFT (blocks 0..159)
__global__ __launch_bounds__(256) void k_amin_ifftu(const float* __restrict__ loss,
                                                    const float* __restrict__ prm,
                                                    const float* __restrict__ cand,
                                                    float* __restrict__ out,
                                                    float2* __restrict__ G) {
  __shared__ float sl[256];
  __shared__ int si[256];
  __shared__ float xr[NF], xi[NF];
  int c1 = threadIdx.x, c2 = threadIdx.x + 256;
  float s1 = loss[c1], s2 = loss[c2];
  float l; int i;
  if (s2 < s1) { l = s2; i = c2; } else { l = s1; i = c1; }
  sl[threadIdx.x] = l; si[threadIdx.x] = i;
  __syncthreads();
  for (int off = 128; off > 0; off >>= 1) {
    if (threadIdx.x < off) {
      float l2 = sl[threadIdx.x + off]; int i2 = si[threadIdx.x + off];
      if (l2 < sl[threadIdx.x] || (l2 == sl[threadIdx.x] && i2 < si[threadIdx.x])) {
        sl[threadIdx.x] = l2; si[threadIdx.x] = i2;
      }
    }
    __syncthreads();
  }
  int bi = si[0];
  if (blockIdx.x == 0 && threadIdx.x == 0) {
    out[6400] = cand[bi * 3 + 0];
    out[6401] = cand[bi * 3 + 1];
    out[6402] = cand[bi * 3 + 2];
    out[6403] = sl[0] * (1.f / 1638400.f);
  }
  int u = blockIdx.x;
  float dc = cand[bi * 3 + 0], xx = cand[bi * 3 + 1], yy = cand[bi * 3 + 2];
  int v = threadIdx.x;
  if (v < NF) {
    float sign = 1.f;
    int ph;
    if (v <= 80) {
      ph = u * NV + v;
    } else {
      int u2 = (NF - u) % NF;
      ph = u2 * NV + (NF - v);
      sign = -1.f;
    }
    float Ar = prm[IP_AR * NPIXP + ph], Ai = prm[IP_AI * NPIXP + ph];
    float Br = prm[IP_BR * NPIXP + ph], Bi = prm[IP_BI * NPIXP + ph];
    float Pm = prm[IP_P * NPIXP + ph], Qm = prm[IP_Q * NPIXP + ph], Rm = prm[IP_R * NPIXP + ph];
    float c2t = prm[IP_C2T * NPIXP + ph], s2t = prm[IP_S2T * NPIXP + ph];
    float k = prm[IP_K * NPIXP + ph];
    float w_ = fmaf(xx, c2t, fmaf(yy, s2t, dc));
    float sw, cw;
    sincosf(k * w_, &sw, &cw);
    float rr = fmaf(cw, Ar, sw * Br);
    float ri = fmaf(cw, Ai, sw * Bi);
    float lhs = fmaf(cw * cw, Pm, fmaf(2.f * cw * sw, Qm, sw * sw * Rm));
    xr[v] = rr / lhs;
    xi[v] = sign * ri / lhs;
  }
  __syncthreads();
  int b = threadIdx.x;
  if (b < NP) {
    int xb = (b + 120) % NF;
    float stc, sts;
    sincosf(TWO_PI * (float)xb / (float)NF, &sts, &stc);
    float c = 1.f, s = 0.f, accR = 0.f, accI = 0.f;
#pragma unroll 4
    for (int vv = 0; vv < NF; ++vv) {
      float xrv = xr[vv], xiv = xi[vv];
      accR = fmaf(xrv, c, accR); accR = fmaf(-xiv, s, accR);
      accI = fmaf(xrv, s, accI); accI = fmaf(xiv, c, accI);
      rot(c, s, stc, sts);
    }
    G[(size_t)u * NP + b] = make_float2(accR, accI);
  }
}

// K5: ifft_y u-sliced 4-way: block = 4 slices x 64 outputs, grid = 100.
__global__ __launch_bounds__(256) void k_ifft_y(const float2* __restrict__ G,
                                                float* __restrict__ out) {
  __shared__ float red[4][65];
  int t = threadIdx.x;
  int o = t & 63;
  int slc = t >> 6;                           // 0..3, u in [40*slc, 40*slc+40)
  int idx = blockIdx.x * 64 + o;              // 6400 outputs
  int b = idx % NP;
  int a = idx / NP;
  int ya = (a + 120) % NF;
  float stc, sts;
  sincosf(TWO_PI * (float)ya / (float)NF, &sts, &stc);
  float c, s;
  start_i_pow(ya * slc, c, s);                // e^{2pi i ya (40 slc)/160} = i^(ya slc)
  float accR = 0.f;
  const float2* Gb = G + (size_t)(slc * 40) * NP + b;
#pragma unroll 4
  for (int j = 0; j < 40; ++j) {
    float2 g = Gb[(size_t)j * NP];
    accR = fmaf(g.x, c, accR);
    accR = fmaf(-g.y, s, accR);
    rot(c, s, stc, sts);
  }
  red[slc][o] = accR;
  __syncthreads();
  if (t < 64) {
    float s4 = ((red[0][t] + red[1][t]) + (red[2][t] + red[3][t]));
    out[blockIdx.x * 64 + t] = s4 * (1.f / 25600.f);
  }
}

extern "C" void kernel_launch(void* const* d_in, const int* in_sizes, int n_in,
                              void* d_out, int out_size, void* d_ws, size_t ws_size,
                              hipStream_t stream) {
  (void)in_sizes; (void)n_in; (void)out_size; (void)ws_size;
  const float* patch  = (const float*)d_in[0];
  const float* gw     = (const float*)d_in[1];
  const float* delays = (const float*)d_in[2];
  const float* theta  = (const float*)d_in[4];
  const float* kloss  = (const float*)d_in[5];
  const float* cand   = (const float*)d_in[6];
  float* out = (float*)d_out;

  char* ws = (char*)d_ws;
  size_t off = 0;
  float2* Y = (float2*)(ws + off);      off += (size_t)ND * NF * NV * 8;     // 6,635,520
  float* prm = (float*)(ws + off);      off += (size_t)NPRM * NPIXP * 4;     //   522,240
  float* partial = (float*)(ws + off);  off += (size_t)NSTR * NC * 4;        // 3,342,336
  float* loss = (float*)(ws + off);     off += (size_t)NC * 4;               //     2,048
  float2* G = (float2*)(ws + off);      off += (size_t)NF * NP * 8;          //   102,400

  hipLaunchKernelGGL(k_fft_xy, dim3(ND * 9), dim3(256), 0, stream, patch, gw, Y);
  hipLaunchKernelGGL(k_cand, dim3(NSTR), dim3(BT), 0, stream, Y, delays, kloss, theta, cand, partial, prm);
  hipLaunchKernelGGL(k_sum, dim3(NC), dim3(256), 0, stream, partial, loss);
  hipLaunchKernelGGL(k_amin_ifftu, dim3(NF), dim3(256), 0, stream, loss, prm, cand, out, G);
  hipLaunchKernelGGL(k_ifft_y, dim3(100), dim3(256), 0, stream, G, out);
}

// Round 18
// 88.454 us; speedup vs baseline: 1.0411x; 1.0411x over previous
//
#include <hip/hip_runtime.h>

#define NF 160
#define NP 80
#define ND 64
#define NC 512
#define NV 81                  // stored v columns 0..80 (Hermitian half)
#define NPIXH (NF*NV)          // 12960
#define NPIXP 13056            // padded: 1632*8
#define NSTR 1632              // pixel stripes (grid.x of k_cand)
#define STRIPE 8               // pixels per stripe
#define RECQ 21                // float4 planes per pixel record (LDS-only)
#define BT 128                 // k_cand block threads
#define CPT 4                  // candidates per thread (128*4 = 512 = NC)
#define TWO_PI 6.283185307179586f

// per-pixel precomputed parameter slots (for k_amin_ifftu)
#define IP_AR 0
#define IP_AI 1
#define IP_BR 2
#define IP_BI 3
#define IP_P  4
#define IP_Q  5
#define IP_R  6
#define IP_C2T 7
#define IP_S2T 8
#define IP_K  9
#define NPRM 10

__device__ __forceinline__ void rot(float& c, float& s, float stc, float sts) {
  float t1 = s * sts;
  float t2 = s * stc;
  float cn = fmaf(c, stc, -t1);
  s = fmaf(c, sts, t2);
  c = cn;
}

__device__ __forceinline__ void start_i_pow(int n, float& c, float& s) {
  switch (n & 3) {
    case 0: c = 1.f; s = 0.f; break;
    case 1: c = 0.f; s = 1.f; break;
    case 2: c = -1.f; s = 0.f; break;
    default: c = 0.f; s = -1.f; break;
  }
}

// K1: T[d][a][v] = sum_b yw[d,a,b] * e^{-2pi i v (b-40)/160}, v in 0..80
__global__ __launch_bounds__(256) void k_fft_x(const float* __restrict__ patch,
                                               const float* __restrict__ gw,
                                               float2* __restrict__ T) {
  int idx = blockIdx.x * 256 + threadIdx.x;   // ND*NP*NV = 414720
  int v = idx % NV;
  int a = (idx / NV) % NP;
  int d = idx / (NV * NP);
  float c, s;
  start_i_pow(v, c, s);
  float stc, sts;
  sincosf(-TWO_PI * (float)v / (float)NF, &sts, &stc);
  const float* prow = patch + (size_t)(d * NP + a) * NP;
  const float* grow = gw + a * NP;
  float accR = 0.f, accI = 0.f;
#pragma unroll 4
  for (int b = 0; b < NP; ++b) {
    float f = prow[b] * grow[b];
    accR = fmaf(f, c, accR);
    accI = fmaf(f, s, accI);
    rot(c, s, stc, sts);
  }
  T[idx] = make_float2(accR, accI);
}

// K2: Y[d][u][v] = sum_a T[d][a][v] * e^{-2pi i u (a-40)/160}
__global__ __launch_bounds__(256) void k_fft_y(const float2* __restrict__ T,
                                               float2* __restrict__ Y) {
  int idx = blockIdx.x * 256 + threadIdx.x;   // 64*40*81 = 207360
  int v = idx % NV;
  int ug = (idx / NV) % 40;
  int d = idx / (NV * 40);
  float c[4], s[4], aR[4], aI[4], stc[4], sts[4];
#pragma unroll
  for (int j = 0; j < 4; ++j) {
    int u = ug * 4 + j;
    start_i_pow(u, c[j], s[j]);
    sincosf(-TWO_PI * (float)u / (float)NF, &sts[j], &stc[j]);
    aR[j] = 0.f; aI[j] = 0.f;
  }
  const float2* Tb = T + (size_t)(d * NP) * NV + v;
#pragma unroll 4
  for (int a = 0; a < NP; ++a) {
    float2 t = Tb[(size_t)a * NV];
#pragma unroll
    for (int j = 0; j < 4; ++j) {
      aR[j] = fmaf(t.x, c[j], aR[j]);
      aR[j] = fmaf(-t.y, s[j], aR[j]);
      aI[j] = fmaf(t.x, s[j], aI[j]);
      aI[j] = fmaf(t.y, c[j], aI[j]);
      rot(c[j], s[j], stc[j], sts[j]);
    }
  }
#pragma unroll
  for (int j = 0; j < 4; ++j) {
    int u = ug * 4 + j;
    Y[((size_t)d * NF + u) * NV + v] = make_float2(aR[j], aI[j]);
  }
}

// K3: fused prep+cand (R16-identical). Block owns an exclusive 8-pixel stripe.
__global__ __launch_bounds__(BT) void k_cand(const float2* __restrict__ Y,
                                             const float* __restrict__ delays,
                                             const float* __restrict__ kloss,
                                             const float* __restrict__ theta,
                                             const float* __restrict__ cand,
                                             float* __restrict__ partial,
                                             float* __restrict__ prm) {
  __shared__ float4 buf[STRIPE][RECQ];        // 2688 B record
  __shared__ float ykl[STRIPE][65];           // 2080 B (padded)
  int t = threadIdx.x;
  int p0 = blockIdx.x * STRIPE;               // 1632*8 = 13056 exactly

  // ---- prep phase ----
  {
    int px = t >> 4;                          // 0..7
    int dg = t & 15;                          // 0..15
    int p = p0 + px;
    bool valid = p < NPIXH;
    float k = 0.f, c2t = 0.f, s2t = 0.f, wgt = 0.f;
    int u = 0, v = 0;
    if (valid) {
      u = p / NV; v = p - u * NV;
      k = kloss[u * NF + v];
      float th = theta[((u + 80) % NF) * NF + ((v + 80) % NF)];
      c2t = cosf(2.f * th); s2t = sinf(2.f * th);
      if (v == 0 || v == 80) {
        if (u == 0 || u == 80) wgt = 1.f;
        else if (u < 80) wgt = 2.f;
        else wgt = 0.f;
      } else wgt = 2.f;
    }
    float mAr = 0.f, mAi = 0.f, mBr = 0.f, mBi = 0.f;
    float mP = 0.f, mQ = 0.f, mR = 0.f, mS = 0.f;
    float cd0t = 1.f, sd0t = 0.f, cd1t = 1.f, sd1t = 0.f;
#pragma unroll
    for (int j = 0; j < 4; ++j) {
      int d = dg * 4 + j;
      float sd, cd;
      sincosf(k * delays[d], &sd, &cd);
      float yx = 0.f, yy = 0.f;
      if (valid) {
        float2 y = Y[((size_t)d * NF + u) * NV + v];
        yx = y.x; yy = y.y;
      }
      mAr = fmaf(yx, cd, mAr);  mAi = fmaf(yy, cd, mAi);
      mBr = fmaf(yx, sd, mBr);  mBi = fmaf(yy, sd, mBi);
      mP = fmaf(cd, cd, mP);  mQ = fmaf(cd, sd, mQ);  mR = fmaf(sd, sd, mR);
      float yk = sqrtf(fmaf(yx, yx, yy * yy)) * k;
      ykl[px][d] = yk;
      mS = fmaf(yk, yk, mS);
      if (j == 0) { cd0t = cd; sd0t = sd; }
      if (j == 1) { cd1t = cd; sd1t = sd; }
    }
#pragma unroll
    for (int off = 8; off > 0; off >>= 1) {
      mAr += __shfl_xor(mAr, off);
      mAi += __shfl_xor(mAi, off);
      mBr += __shfl_xor(mBr, off);
      mBi += __shfl_xor(mBi, off);
      mP += __shfl_xor(mP, off);
      mQ += __shfl_xor(mQ, off);
      mR += __shfl_xor(mR, off);
      mS += __shfl_xor(mS, off);
    }
    if (dg == 0) {
      if (valid) {
        float tcd = 2.f * cosf(k * (delays[1] - delays[0]));
        buf[px][16] = make_float4(mAr, mAi, mBr, mBi);
        buf[px][17] = make_float4(mP, mQ, mR, mS);
        buf[px][18] = make_float4(c2t, s2t, k, wgt);
        buf[px][19] = make_float4(cd0t, sd0t, cd1t, sd1t);
        buf[px][20] = make_float4(tcd, 0.f, 0.f, 0.f);
        prm[IP_AR * NPIXP + p] = mAr;  prm[IP_AI * NPIXP + p] = mAi;
        prm[IP_BR * NPIXP + p] = mBr;  prm[IP_BI * NPIXP + p] = mBi;
        prm[IP_P * NPIXP + p] = mP;    prm[IP_Q * NPIXP + p] = mQ;
        prm[IP_R * NPIXP + p] = mR;    prm[IP_C2T * NPIXP + p] = c2t;
        prm[IP_S2T * NPIXP + p] = s2t; prm[IP_K * NPIXP + p] = k;
      } else {
        buf[px][16] = make_float4(0.f, 0.f, 0.f, 0.f);
        buf[px][17] = make_float4(1.f, 0.f, 1.f, 0.f);
        buf[px][18] = make_float4(0.f, 0.f, 0.f, 0.f);
        buf[px][19] = make_float4(1.f, 0.f, 1.f, 0.f);
        buf[px][20] = make_float4(2.f, 0.f, 0.f, 0.f);
      }
    }
    int px2 = t >> 4, jj = t & 15;
    buf[px2][jj] = make_float4(ykl[px2][2 * jj], ykl[px2][63 - 2 * jj],
                               ykl[px2][2 * jj + 1], ykl[px2][62 - 2 * jj]);
  }
  __syncthreads();

  // ---- candidate phase ----
  float dc[CPT], xx[CPT], yy[CPT], acc[CPT];
#pragma unroll
  for (int ci = 0; ci < CPT; ++ci) {
    int c = t + ci * BT;
    dc[ci] = cand[c * 3 + 0];
    xx[ci] = cand[c * 3 + 1];
    yy[ci] = cand[c * 3 + 2];
    acc[ci] = 0.f;
  }
#pragma unroll
  for (int i = 0; i < STRIPE; ++i) {
    const float4* r = &buf[i][0];
    float4 pA = r[16];                        // Ar,Ai,Br,Bi
    float4 pB = r[17];                        // Pm,Qm,Rm,S0
    float4 pC = r[18];                        // c2t,s2t,k,wgt
    float4 pD = r[19];                        // cd0,sd0,cd1,sd1
    float tcd = r[20].x;
    float4 y0 = r[0];
    float A0[CPT], A1[CPT], B0[CPT], B1[CPT], M[CPT], F0[CPT], F1[CPT];
#pragma unroll
    for (int ci = 0; ci < CPT; ++ci) {
      float w_ = fmaf(xx[ci], pC.x, fmaf(yy[ci], pC.y, dc[ci]));
      float sw, cw;
      __sincosf(pC.z * w_, &sw, &cw);
      float rr = fmaf(cw, pA.x, sw * pA.z);
      float ri = fmaf(cw, pA.y, sw * pA.w);
      float lhs = fmaf(cw * cw, pB.x, fmaf(2.f * cw * sw, pB.y, sw * sw * pB.z));
      float rabs = __builtin_amdgcn_sqrtf(fmaf(rr, rr, ri * ri));
      float rl = __builtin_amdgcn_rcpf(lhs);
      float e = fmaf(-lhs, rl, 1.f);
      rl = fmaf(rl, e, rl);                   // refined 1/lhs
      float kX = pC.z * rabs * rl;
      F0[ci] = fmaf(kX * kX, lhs, pB.w);      // contrib = F0 + F1*M
      F1[ci] = -2.f * kX;
      float t0 = pD.x * cw, u0 = pD.y * sw;
      float t1 = pD.z * cw, u1 = pD.w * sw;
      A0[ci] = t0 + u0;  B0[ci] = t0 - u0;    // cos(k d0 -/+ kw)
      A1[ci] = t1 + u1;  B1[ci] = t1 - u1;    // cos(k d1 -/+ kw)
      float m = y0.x * fabsf(A0[ci]);
      m = fmaf(y0.y, fabsf(B0[ci]), m);
      m = fmaf(y0.z, fabsf(A1[ci]), m);
      m = fmaf(y0.w, fabsf(B1[ci]), m);
      M[ci] = m;
    }
    float4 ykn = r[1];
#pragma unroll
    for (int jj = 1; jj < 16; ++jj) {
      float4 yk = ykn;
      if (jj < 15) ykn = r[jj + 1];           // 1-ahead prefetch
#pragma unroll
      for (int ci = 0; ci < CPT; ++ci) {
        float An = fmaf(tcd, A1[ci], -A0[ci]);
        float Bn = fmaf(tcd, B1[ci], -B0[ci]);
        float m = fmaf(yk.x, fabsf(An), M[ci]);
        m = fmaf(yk.y, fabsf(Bn), m);
        float An2 = fmaf(tcd, An, -A1[ci]);
        float Bn2 = fmaf(tcd, Bn, -B1[ci]);
        m = fmaf(yk.z, fabsf(An2), m);
        m = fmaf(yk.w, fabsf(Bn2), m);
        M[ci] = m;
        A0[ci] = An; A1[ci] = An2;
        B0[ci] = Bn; B1[ci] = Bn2;
      }
    }
#pragma unroll
    for (int ci = 0; ci < CPT; ++ci)
      acc[ci] = fmaf(fmaf(F1[ci], M[ci], F0[ci]), pC.w, acc[ci]);
  }
#pragma unroll
  for (int ci = 0; ci < CPT; ++ci)
    partial[(size_t)blockIdx.x * NC + t + ci * BT] = acc[ci];
}

// K4: loss[c] = sum over stripes — one block per candidate, parallel loads,
// deterministic LDS tree reduction.
__global__ __launch_bounds__(256) void k_sum(const float* __restrict__ partial,
                                             float* __restrict__ loss) {
  __shared__ float red[256];
  int c = blockIdx.x;                         // 512 blocks
  float s = 0.f;
  for (int j = threadIdx.x; j < NSTR; j += 256)
    s += partial[(size_t)j * NC + c];
  red[threadIdx.x] = s;
  __syncthreads();
  for (int off = 128; off > 0; off >>= 1) {
    if (threadIdx.x < off) red[threadIdx.x] += red[threadIdx.x + off];
    __syncthreads();
  }
  if (threadIdx.x == 0) loss[c] = red[0];
}

// K5: fused redundant argmin + ifft_u (2-way v-sliced row DFT), blocks 0..159.
__global__ __launch_bounds__(256) void k_amin_ifftu(const float* __restrict__ loss,
                                                    const float* __restrict__ prm,
                                                    const float* __restrict__ cand,
                                                    float* __restrict__ out,
                                                    float2* __restrict__ G) {
  __shared__ float sl[256];
  __shared__ int si[256];
  __shared__ float xr[NF], xi[NF];
  __shared__ float2 gred[2][NP];
  int c1 = threadIdx.x, c2 = threadIdx.x + 256;
  float s1 = loss[c1], s2 = loss[c2];
  float l; int i;
  if (s2 < s1) { l = s2; i = c2; } else { l = s1; i = c1; }
  sl[threadIdx.x] = l; si[threadIdx.x] = i;
  __syncthreads();
  for (int off = 128; off > 0; off >>= 1) {
    if (threadIdx.x < off) {
      float l2 = sl[threadIdx.x + off]; int i2 = si[threadIdx.x + off];
      if (l2 < sl[threadIdx.x] || (l2 == sl[threadIdx.x] && i2 < si[threadIdx.x])) {
        sl[threadIdx.x] = l2; si[threadIdx.x] = i2;
      }
    }
    __syncthreads();
  }
  int bi = si[0];
  if (blockIdx.x == 0 && threadIdx.x == 0) {
    out[6400] = cand[bi * 3 + 0];
    out[6401] = cand[bi * 3 + 1];
    out[6402] = cand[bi * 3 + 2];
    out[6403] = sl[0] * (1.f / 1638400.f);
  }
  int u = blockIdx.x;
  float dc = cand[bi * 3 + 0], xx = cand[bi * 3 + 1], yy = cand[bi * 3 + 2];
  int v = threadIdx.x;
  if (v < NF) {
    float sign = 1.f;
    int ph;
    if (v <= 80) {
      ph = u * NV + v;
    } else {
      int u2 = (NF - u) % NF;
      ph = u2 * NV + (NF - v);
      sign = -1.f;
    }
    float Ar = prm[IP_AR * NPIXP + ph], Ai = prm[IP_AI * NPIXP + ph];
    float Br = prm[IP_BR * NPIXP + ph], Bi = prm[IP_BI * NPIXP + ph];
    float Pm = prm[IP_P * NPIXP + ph], Qm = prm[IP_Q * NPIXP + ph], Rm = prm[IP_R * NPIXP + ph];
    float c2t = prm[IP_C2T * NPIXP + ph], s2t = prm[IP_S2T * NPIXP + ph];
    float k = prm[IP_K * NPIXP + ph];
    float w_ = fmaf(xx, c2t, fmaf(yy, s2t, dc));
    float sw, cw;
    sincosf(k * w_, &sw, &cw);
    float rr = fmaf(cw, Ar, sw * Br);
    float ri = fmaf(cw, Ai, sw * Bi);
    float lhs = fmaf(cw * cw, Pm, fmaf(2.f * cw * sw, Qm, sw * sw * Rm));
    xr[v] = rr / lhs;
    xi[v] = sign * ri / lhs;
  }
  __syncthreads();
  int tb = threadIdx.x;
  if (tb < 2 * NP) {
    int slc = tb >= NP ? 1 : 0;
    int b = tb - slc * NP;
    int xb = (b + 120) % NF;
    float stc, sts;
    sincosf(TWO_PI * (float)xb / (float)NF, &sts, &stc);
    // start phase for v-slice: e^{2pi i xb (80 slc)/160} = (-1)^(xb*slc)
    float c = (slc && (xb & 1)) ? -1.f : 1.f;
    float s = 0.f;
    float accR = 0.f, accI = 0.f;
    int v0 = slc * NP;
#pragma unroll 4
    for (int vv = 0; vv < NP; ++vv) {
      float xrv = xr[v0 + vv], xiv = xi[v0 + vv];
      accR = fmaf(xrv, c, accR); accR = fmaf(-xiv, s, accR);
      accI = fmaf(xrv, s, accI); accI = fmaf(xiv, c, accI);
      rot(c, s, stc, sts);
    }
    gred[slc][b] = make_float2(accR, accI);
  }
  __syncthreads();
  if (tb < NP) {
    float2 g0 = gred[0][tb], g1 = gred[1][tb];
    G[(size_t)u * NP + tb] = make_float2(g0.x + g1.x, g0.y + g1.y);
  }
}

// K6: ifft_y 8-way u-sliced: block = 8 slices x 32 outputs, grid = 200.
__global__ __launch_bounds__(256) void k_ifft_y(const float2* __restrict__ G,
                                                float* __restrict__ out) {
  __shared__ float red[8][33];
  int t = threadIdx.x;
  int o = t & 31;
  int slc = t >> 5;                           // 0..7, u in [20*slc, 20*slc+20)
  int idx = blockIdx.x * 32 + o;              // 200*32 = 6400 outputs
  int b = idx % NP;
  int a = idx / NP;
  int ya = (a + 120) % NF;
  float stc, sts;
  sincosf(TWO_PI * (float)ya / (float)NF, &sts, &stc);
  // start phase: e^{2pi i ya (20 slc)/160}
  float ang = TWO_PI * (float)((ya * slc * 20) % NF) / (float)NF;
  float c, s;
  sincosf(ang, &s, &c);
  float accR = 0.f;
  const float2* Gb = G + (size_t)(slc * 20) * NP + b;
#pragma unroll 4
  for (int j = 0; j < 20; ++j) {
    float2 g = Gb[(size_t)j * NP];
    accR = fmaf(g.x, c, accR);
    accR = fmaf(-g.y, s, accR);
    rot(c, s, stc, sts);
  }
  red[slc][o] = accR;
  __syncthreads();
  if (t < 32) {
    float s8 = ((red[0][t] + red[1][t]) + (red[2][t] + red[3][t]))
             + ((red[4][t] + red[5][t]) + (red[6][t] + red[7][t]));
    out[blockIdx.x * 32 + t] = s8 * (1.f / 25600.f);
  }
}

extern "C" void kernel_launch(void* const* d_in, const int* in_sizes, int n_in,
                              void* d_out, int out_size, void* d_ws, size_t ws_size,
                              hipStream_t stream) {
  (void)in_sizes; (void)n_in; (void)out_size; (void)ws_size;
  const float* patch  = (const float*)d_in[0];
  const float* gw     = (const float*)d_in[1];
  const float* delays = (const float*)d_in[2];
  const float* theta  = (const float*)d_in[4];
  const float* kloss  = (const float*)d_in[5];
  const float* cand   = (const float*)d_in[6];
  float* out = (float*)d_out;

  char* ws = (char*)d_ws;
  size_t off = 0;
  float2* Y = (float2*)(ws + off);      off += (size_t)ND * NF * NV * 8;     // 6,635,520
  float2* T = (float2*)(ws + off);      off += (size_t)ND * NP * NV * 8;     // 3,317,760
  float* prm = (float*)(ws + off);      off += (size_t)NPRM * NPIXP * 4;     //   522,240
  float* partial = (float*)(ws + off);  off += (size_t)NSTR * NC * 4;        // 3,342,336
  float* loss = (float*)(ws + off);     off += (size_t)NC * 4;               //     2,048
  float2* G = (float2*)(ws + off);      off += (size_t)NF * NP * 8;          //   102,400

  hipLaunchKernelGGL(k_fft_x, dim3((ND * NP * NV) / 256), dim3(256), 0, stream, patch, gw, T);
  hipLaunchKernelGGL(k_fft_y, dim3((ND * 40 * NV) / 256), dim3(256), 0, stream, T, Y);
  hipLaunchKernelGGL(k_cand, dim3(NSTR), dim3(BT), 0, stream, Y, delays, kloss, theta, cand, partial, prm);
  hipLaunchKernelGGL(k_sum, dim3(NC), dim3(256), 0, stream, partial, loss);
  hipLaunchKernelGGL(k_amin_ifftu, dim3(NF), dim3(256), 0, stream, loss, prm, cand, out, G);
  hipLaunchKernelGGL(k_ifft_y, dim3(200), dim3(256), 0, stream, G, out);
}

// Round 19
// 87.027 us; speedup vs baseline: 1.0581x; 1.0164x over previous
//
#include <hip/hip_runtime.h>

#define NF 160
#define NP 80
#define ND 64
#define NC 512
#define NV 81                  // stored v columns 0..80 (Hermitian half)
#define NPIXH (NF*NV)          // 12960
#define NPIXP 13056            // padded: 1632*8
#define NSTR 1632              // pixel stripes (grid.x of k_cand)
#define STRIPE 8               // pixels per stripe
#define RECQ 21                // float4 planes per pixel record (LDS-only)
#define BT 128                 // k_cand block threads
#define CPT 4                  // candidates per thread (128*4 = 512 = NC)
#define TWO_PI 6.283185307179586f

// per-pixel precomputed parameter slots (for k_amin_ifftu)
#define IP_AR 0
#define IP_AI 1
#define IP_BR 2
#define IP_BI 3
#define IP_P  4
#define IP_Q  5
#define IP_R  6
#define IP_C2T 7
#define IP_S2T 8
#define IP_K  9
#define NPRM 10

__device__ __forceinline__ void rot(float& c, float& s, float stc, float sts) {
  float t1 = s * sts;
  float t2 = s * stc;
  float cn = fmaf(c, stc, -t1);
  s = fmaf(c, sts, t2);
  c = cn;
}

__device__ __forceinline__ void start_i_pow(int n, float& c, float& s) {
  switch (n & 3) {
    case 0: c = 1.f; s = 0.f; break;
    case 1: c = 0.f; s = 1.f; break;
    case 2: c = -1.f; s = 0.f; break;
    default: c = 0.f; s = -1.f; break;
  }
}

// K1: T[d][a][v] = sum_b yw[d,a,b] * e^{-2pi i v (b-40)/160}, v in 0..80
__global__ __launch_bounds__(256) void k_fft_x(const float* __restrict__ patch,
                                               const float* __restrict__ gw,
                                               float2* __restrict__ T) {
  int idx = blockIdx.x * 256 + threadIdx.x;   // ND*NP*NV = 414720
  int v = idx % NV;
  int a = (idx / NV) % NP;
  int d = idx / (NV * NP);
  float c, s;
  start_i_pow(v, c, s);
  float stc, sts;
  sincosf(-TWO_PI * (float)v / (float)NF, &sts, &stc);
  const float* prow = patch + (size_t)(d * NP + a) * NP;
  const float* grow = gw + a * NP;
  float accR = 0.f, accI = 0.f;
#pragma unroll 4
  for (int b = 0; b < NP; ++b) {
    float f = prow[b] * grow[b];
    accR = fmaf(f, c, accR);
    accI = fmaf(f, s, accI);
    rot(c, s, stc, sts);
  }
  T[idx] = make_float2(accR, accI);
}

// K2: Y[d][u][v] = sum_a T[d][a][v] * e^{-2pi i u (a-40)/160}
__global__ __launch_bounds__(256) void k_fft_y(const float2* __restrict__ T,
                                               float2* __restrict__ Y) {
  int idx = blockIdx.x * 256 + threadIdx.x;   // 64*40*81 = 207360
  int v = idx % NV;
  int ug = (idx / NV) % 40;
  int d = idx / (NV * 40);
  float c[4], s[4], aR[4], aI[4], stc[4], sts[4];
#pragma unroll
  for (int j = 0; j < 4; ++j) {
    int u = ug * 4 + j;
    start_i_pow(u, c[j], s[j]);
    sincosf(-TWO_PI * (float)u / (float)NF, &sts[j], &stc[j]);
    aR[j] = 0.f; aI[j] = 0.f;
  }
  const float2* Tb = T + (size_t)(d * NP) * NV + v;
#pragma unroll 4
  for (int a = 0; a < NP; ++a) {
    float2 t = Tb[(size_t)a * NV];
#pragma unroll
    for (int j = 0; j < 4; ++j) {
      aR[j] = fmaf(t.x, c[j], aR[j]);
      aR[j] = fmaf(-t.y, s[j], aR[j]);
      aI[j] = fmaf(t.x, s[j], aI[j]);
      aI[j] = fmaf(t.y, c[j], aI[j]);
      rot(c[j], s[j], stc[j], sts[j]);
    }
  }
#pragma unroll
  for (int j = 0; j < 4; ++j) {
    int u = ug * 4 + j;
    Y[((size_t)d * NF + u) * NV + v] = make_float2(aR[j], aI[j]);
  }
}

// K3: fused prep+cand. Block owns an exclusive 8-pixel stripe.
__global__ __launch_bounds__(BT) void k_cand(const float2* __restrict__ Y,
                                             const float* __restrict__ delays,
                                             const float* __restrict__ kloss,
                                             const float* __restrict__ theta,
                                             const float* __restrict__ cand,
                                             float* __restrict__ partial,
                                             float* __restrict__ prm) {
  __shared__ float4 buf[STRIPE][RECQ];        // 2688 B record
  __shared__ float ykl[STRIPE][65];           // 2080 B (padded)
  int t = threadIdx.x;
  int p0 = blockIdx.x * STRIPE;               // 1632*8 = 13056 exactly

  // ---- prep phase ----
  {
    int px = t >> 4;                          // 0..7
    int dg = t & 15;                          // 0..15
    int p = p0 + px;
    bool valid = p < NPIXH;
    float k = 0.f, c2t = 0.f, s2t = 0.f, wgt = 0.f;
    int u = 0, v = 0;
    if (valid) {
      u = p / NV; v = p - u * NV;
      k = kloss[u * NF + v];
      float th = theta[((u + 80) % NF) * NF + ((v + 80) % NF)];
      c2t = cosf(2.f * th); s2t = sinf(2.f * th);
      if (v == 0 || v == 80) {
        if (u == 0 || u == 80) wgt = 1.f;
        else if (u < 80) wgt = 2.f;
        else wgt = 0.f;
      } else wgt = 2.f;
    }
    float mAr = 0.f, mAi = 0.f, mBr = 0.f, mBi = 0.f;
    float mP = 0.f, mQ = 0.f, mR = 0.f, mS = 0.f;
    float cd0t = 1.f, sd0t = 0.f, cd1t = 1.f, sd1t = 0.f;
    // one base sincos + step rotation (delays are linspace)
    float dstep = delays[1] - delays[0];
    float cd, sd, cst, sst;
    sincosf(k * delays[dg * 4], &sd, &cd);
    sincosf(k * dstep, &sst, &cst);
#pragma unroll
    for (int j = 0; j < 4; ++j) {
      int d = dg * 4 + j;
      float yx = 0.f, yy = 0.f;
      if (valid) {
        float2 y = Y[((size_t)d * NF + u) * NV + v];
        yx = y.x; yy = y.y;
      }
      mAr = fmaf(yx, cd, mAr);  mAi = fmaf(yy, cd, mAi);
      mBr = fmaf(yx, sd, mBr);  mBi = fmaf(yy, sd, mBi);
      mP = fmaf(cd, cd, mP);  mQ = fmaf(cd, sd, mQ);  mR = fmaf(sd, sd, mR);
      float yk = sqrtf(fmaf(yx, yx, yy * yy)) * k;
      ykl[px][d] = yk;
      mS = fmaf(yk, yk, mS);
      if (j == 0) { cd0t = cd; sd0t = sd; }
      if (j == 1) { cd1t = cd; sd1t = sd; }
      rot(cd, sd, cst, sst);
    }
#pragma unroll
    for (int off = 8; off > 0; off >>= 1) {
      mAr += __shfl_xor(mAr, off);
      mAi += __shfl_xor(mAi, off);
      mBr += __shfl_xor(mBr, off);
      mBi += __shfl_xor(mBi, off);
      mP += __shfl_xor(mP, off);
      mQ += __shfl_xor(mQ, off);
      mR += __shfl_xor(mR, off);
      mS += __shfl_xor(mS, off);
    }
    if (dg == 0) {
      if (valid) {
        float tcd = 2.f * cst;                // cst = cos(k*dstep)
        buf[px][16] = make_float4(mAr, mAi, mBr, mBi);
        buf[px][17] = make_float4(mP, mQ, mR, mS);
        buf[px][18] = make_float4(c2t, s2t, k, wgt);
        buf[px][19] = make_float4(cd0t, sd0t, cd1t, sd1t);
        buf[px][20] = make_float4(tcd, 0.f, 0.f, 0.f);
        prm[IP_AR * NPIXP + p] = mAr;  prm[IP_AI * NPIXP + p] = mAi;
        prm[IP_BR * NPIXP + p] = mBr;  prm[IP_BI * NPIXP + p] = mBi;
        prm[IP_P * NPIXP + p] = mP;    prm[IP_Q * NPIXP + p] = mQ;
        prm[IP_R * NPIXP + p] = mR;    prm[IP_C2T * NPIXP + p] = c2t;
        prm[IP_S2T * NPIXP + p] = s2t; prm[IP_K * NPIXP + p] = k;
      } else {
        buf[px][16] = make_float4(0.f, 0.f, 0.f, 0.f);
        buf[px][17] = make_float4(1.f, 0.f, 1.f, 0.f);
        buf[px][18] = make_float4(0.f, 0.f, 0.f, 0.f);
        buf[px][19] = make_float4(1.f, 0.f, 1.f, 0.f);
        buf[px][20] = make_float4(2.f, 0.f, 0.f, 0.f);
      }
    }
    int px2 = t >> 4, jj = t & 15;
    buf[px2][jj] = make_float4(ykl[px2][2 * jj], ykl[px2][63 - 2 * jj],
                               ykl[px2][2 * jj + 1], ykl[px2][62 - 2 * jj]);
  }
  __syncthreads();

  // ---- candidate phase ----
  float dc[CPT], xx[CPT], yy[CPT], acc[CPT];
#pragma unroll
  for (int ci = 0; ci < CPT; ++ci) {
    int c = t + ci * BT;
    dc[ci] = cand[c * 3 + 0];
    xx[ci] = cand[c * 3 + 1];
    yy[ci] = cand[c * 3 + 2];
    acc[ci] = 0.f;
  }
#pragma unroll
  for (int i = 0; i < STRIPE; ++i) {
    const float4* r = &buf[i][0];
    float4 pA = r[16];                        // Ar,Ai,Br,Bi
    float4 pB = r[17];                        // Pm,Qm,Rm,S0
    float4 pC = r[18];                        // c2t,s2t,k,wgt
    float4 pD = r[19];                        // cd0,sd0,cd1,sd1
    float tcd = r[20].x;
    float4 y0 = r[0];
    float A0[CPT], A1[CPT], B0[CPT], B1[CPT], M[CPT], F0[CPT], F1[CPT];
#pragma unroll
    for (int ci = 0; ci < CPT; ++ci) {
      float w_ = fmaf(xx[ci], pC.x, fmaf(yy[ci], pC.y, dc[ci]));
      float sw, cw;
      __sincosf(pC.z * w_, &sw, &cw);
      float rr = fmaf(cw, pA.x, sw * pA.z);
      float ri = fmaf(cw, pA.y, sw * pA.w);
      float lhs = fmaf(cw * cw, pB.x, fmaf(2.f * cw * sw, pB.y, sw * sw * pB.z));
      float rabs = __builtin_amdgcn_sqrtf(fmaf(rr, rr, ri * ri));
      float rl = __builtin_amdgcn_rcpf(lhs);
      float e = fmaf(-lhs, rl, 1.f);
      rl = fmaf(rl, e, rl);                   // refined 1/lhs
      float kX = pC.z * rabs * rl;
      F0[ci] = fmaf(kX * kX, lhs, pB.w);      // contrib = F0 + F1*M
      F1[ci] = -2.f * kX;
      float t0 = pD.x * cw, u0 = pD.y * sw;
      float t1 = pD.z * cw, u1 = pD.w * sw;
      A0[ci] = t0 + u0;  B0[ci] = t0 - u0;    // cos(k d0 -/+ kw)
      A1[ci] = t1 + u1;  B1[ci] = t1 - u1;    // cos(k d1 -/+ kw)
      float m = y0.x * fabsf(A0[ci]);
      m = fmaf(y0.y, fabsf(B0[ci]), m);
      m = fmaf(y0.z, fabsf(A1[ci]), m);
      m = fmaf(y0.w, fabsf(B1[ci]), m);
      M[ci] = m;
    }
    float4 ykn = r[1];
#pragma unroll
    for (int jj = 1; jj < 16; ++jj) {
      float4 yk = ykn;
      if (jj < 15) ykn = r[jj + 1];           // 1-ahead prefetch
#pragma unroll
      for (int ci = 0; ci < CPT; ++ci) {
        float An = fmaf(tcd, A1[ci], -A0[ci]);
        float Bn = fmaf(tcd, B1[ci], -B0[ci]);
        float m = fmaf(yk.x, fabsf(An), M[ci]);
        m = fmaf(yk.y, fabsf(Bn), m);
        float An2 = fmaf(tcd, An, -A1[ci]);
        float Bn2 = fmaf(tcd, Bn, -B1[ci]);
        m = fmaf(yk.z, fabsf(An2), m);
        m = fmaf(yk.w, fabsf(Bn2), m);
        M[ci] = m;
        A0[ci] = An; A1[ci] = An2;
        B0[ci] = Bn; B1[ci] = Bn2;
      }
    }
#pragma unroll
    for (int ci = 0; ci < CPT; ++ci)
      acc[ci] = fmaf(fmaf(F1[ci], M[ci], F0[ci]), pC.w, acc[ci]);
  }
#pragma unroll
  for (int ci = 0; ci < CPT; ++ci)
    partial[(size_t)blockIdx.x * NC + t + ci * BT] = acc[ci];
}

// K4: loss[4cb..4cb+3] = sum over stripes — float4 vectorized, identical
// summation order to the scalar version (j strided by 256, then tree).
__global__ __launch_bounds__(256) void k_sum(const float* __restrict__ partial,
                                             float* __restrict__ loss) {
  __shared__ float4 red[256];
  int cb = blockIdx.x * 4;                    // 128 blocks
  float4 s = make_float4(0.f, 0.f, 0.f, 0.f);
  for (int j = threadIdx.x; j < NSTR; j += 256) {
    float4 p = *(const float4*)(partial + (size_t)j * NC + cb);
    s.x += p.x; s.y += p.y; s.z += p.z; s.w += p.w;
  }
  red[threadIdx.x] = s;
  __syncthreads();
  for (int off = 128; off > 0; off >>= 1) {
    if (threadIdx.x < off) {
      float4 o = red[threadIdx.x + off];
      float4 m = red[threadIdx.x];
      m.x += o.x; m.y += o.y; m.z += o.z; m.w += o.w;
      red[threadIdx.x] = m;
    }
    __syncthreads();
  }
  if (threadIdx.x == 0) *(float4*)(loss + cb) = red[0];
}

// K5: fused redundant argmin + ifft_u (2-way v-sliced row DFT), blocks 0..159.
__global__ __launch_bounds__(256) void k_amin_ifftu(const float* __restrict__ loss,
                                                    const float* __restrict__ prm,
                                                    const float* __restrict__ cand,
                                                    float* __restrict__ out,
                                                    float2* __restrict__ G) {
  __shared__ float sl[256];
  __shared__ int si[256];
  __shared__ float xr[NF], xi[NF];
  __shared__ float2 gred[2][NP];
  int c1 = threadIdx.x, c2 = threadIdx.x + 256;
  float s1 = loss[c1], s2 = loss[c2];
  float l; int i;
  if (s2 < s1) { l = s2; i = c2; } else { l = s1; i = c1; }
  sl[threadIdx.x] = l; si[threadIdx.x] = i;
  __syncthreads();
  for (int off = 128; off > 0; off >>= 1) {
    if (threadIdx.x < off) {
      float l2 = sl[threadIdx.x + off]; int i2 = si[threadIdx.x + off];
      if (l2 < sl[threadIdx.x] || (l2 == sl[threadIdx.x] && i2 < si[threadIdx.x])) {
        sl[threadIdx.x] = l2; si[threadIdx.x] = i2;
      }
    }
    __syncthreads();
  }
  int bi = si[0];
  if (blockIdx.x == 0 && threadIdx.x == 0) {
    out[6400] = cand[bi * 3 + 0];
    out[6401] = cand[bi * 3 + 1];
    out[6402] = cand[bi * 3 + 2];
    out[6403] = sl[0] * (1.f / 1638400.f);
  }
  int u = blockIdx.x;
  float dc = cand[bi * 3 + 0], xx = cand[bi * 3 + 1], yy = cand[bi * 3 + 2];
  int v = threadIdx.x;
  if (v < NF) {
    float sign = 1.f;
    int ph;
    if (v <= 80) {
      ph = u * NV + v;
    } else {
      int u2 = (NF - u) % NF;
      ph = u2 * NV + (NF - v);
      sign = -1.f;
    }
    float Ar = prm[IP_AR * NPIXP + ph], Ai = prm[IP_AI * NPIXP + ph];
    float Br = prm[IP_BR * NPIXP + ph], Bi = prm[IP_BI * NPIXP + ph];
    float Pm = prm[IP_P * NPIXP + ph], Qm = prm[IP_Q * NPIXP + ph], Rm = prm[IP_R * NPIXP + ph];
    float c2t = prm[IP_C2T * NPIXP + ph], s2t = prm[IP_S2T * NPIXP + ph];
    float k = prm[IP_K * NPIXP + ph];
    float w_ = fmaf(xx, c2t, fmaf(yy, s2t, dc));
    float sw, cw;
    sincosf(k * w_, &sw, &cw);
    float rr = fmaf(cw, Ar, sw * Br);
    float ri = fmaf(cw, Ai, sw * Bi);
    float lhs = fmaf(cw * cw, Pm, fmaf(2.f * cw * sw, Qm, sw * sw * Rm));
    xr[v] = rr / lhs;
    xi[v] = sign * ri / lhs;
  }
  __syncthreads();
  int tb = threadIdx.x;
  if (tb < 2 * NP) {
    int slc = tb >= NP ? 1 : 0;
    int b = tb - slc * NP;
    int xb = (b + 120) % NF;
    float stc, sts;
    sincosf(TWO_PI * (float)xb / (float)NF, &sts, &stc);
    // start phase for v-slice: e^{2pi i xb (80 slc)/160} = (-1)^(xb*slc)
    float c = (slc && (xb & 1)) ? -1.f : 1.f;
    float s = 0.f;
    float accR = 0.f, accI = 0.f;
    int v0 = slc * NP;
#pragma unroll 4
    for (int vv = 0; vv < NP; ++vv) {
      float xrv = xr[v0 + vv], xiv = xi[v0 + vv];
      accR = fmaf(xrv, c, accR); accR = fmaf(-xiv, s, accR);
      accI = fmaf(xrv, s, accI); accI = fmaf(xiv, c, accI);
      rot(c, s, stc, sts);
    }
    gred[slc][b] = make_float2(accR, accI);
  }
  __syncthreads();
  if (tb < NP) {
    float2 g0 = gred[0][tb], g1 = gred[1][tb];
    G[(size_t)u * NP + tb] = make_float2(g0.x + g1.x, g0.y + g1.y);
  }
}

// K6: ifft_y 8-way u-sliced: block = 8 slices x 32 outputs, grid = 200.
__global__ __launch_bounds__(256) void k_ifft_y(const float2* __restrict__ G,
                                                float* __restrict__ out) {
  __shared__ float red[8][33];
  int t = threadIdx.x;
  int o = t & 31;
  int slc = t >> 5;                           // 0..7, u in [20*slc, 20*slc+20)
  int idx = blockIdx.x * 32 + o;              // 200*32 = 6400 outputs
  int b = idx % NP;
  int a = idx / NP;
  int ya = (a + 120) % NF;
  float stc, sts;
  sincosf(TWO_PI * (float)ya / (float)NF, &sts, &stc);
  // start phase: e^{2pi i ya (20 slc)/160}
  float ang = TWO_PI * (float)((ya * slc * 20) % NF) / (float)NF;
  float c, s;
  sincosf(ang, &s, &c);
  float accR = 0.f;
  const float2* Gb = G + (size_t)(slc * 20) * NP + b;
#pragma unroll 4
  for (int j = 0; j < 20; ++j) {
    float2 g = Gb[(size_t)j * NP];
    accR = fmaf(g.x, c, accR);
    accR = fmaf(-g.y, s, accR);
    rot(c, s, stc, sts);
  }
  red[slc][o] = accR;
  __syncthreads();
  if (t < 32) {
    float s8 = ((red[0][t] + red[1][t]) + (red[2][t] + red[3][t]))
             + ((red[4][t] + red[5][t]) + (red[6][t] + red[7][t]));
    out[blockIdx.x * 32 + t] = s8 * (1.f / 25600.f);
  }
}

extern "C" void kernel_launch(void* const* d_in, const int* in_sizes, int n_in,
                              void* d_out, int out_size, void* d_ws, size_t ws_size,
                              hipStream_t stream) {
  (void)in_sizes; (void)n_in; (void)out_size; (void)ws_size;
  const float* patch  = (const float*)d_in[0];
  const float* gw     = (const float*)d_in[1];
  const float* delays = (const float*)d_in[2];
  const float* theta  = (const float*)d_in[4];
  const float* kloss  = (const float*)d_in[5];
  const float* cand   = (const float*)d_in[6];
  float* out = (float*)d_out;

  char* ws = (char*)d_ws;
  size_t off = 0;
  float2* Y = (float2*)(ws + off);      off += (size_t)ND * NF * NV * 8;     // 6,635,520
  float2* T = (float2*)(ws + off);      off += (size_t)ND * NP * NV * 8;     // 3,317,760
  float* prm = (float*)(ws + off);      off += (size_t)NPRM * NPIXP * 4;     //   522,240
  float* partial = (float*)(ws + off);  off += (size_t)NSTR * NC * 4;        // 3,342,336
  float* loss = (float*)(ws + off);     off += (size_t)NC * 4;               //     2,048
  float2* G = (float2*)(ws + off);      off += (size_t)NF * NP * 8;          //   102,400

  hipLaunchKernelGGL(k_fft_x, dim3((ND * NP * NV) / 256), dim3(256), 0, stream, patch, gw, T);
  hipLaunchKernelGGL(k_fft_y, dim3((ND * 40 * NV) / 256), dim3(256), 0, stream, T, Y);
  hipLaunchKernelGGL(k_cand, dim3(NSTR), dim3(BT), 0, stream, Y, delays, kloss, theta, cand, partial, prm);
  hipLaunchKernelGGL(k_sum, dim3(NC / 4), dim3(256), 0, stream, partial, loss);
  hipLaunchKernelGGL(k_amin_ifftu, dim3(NF), dim3(256), 0, stream, loss, prm, cand, out, G);
  hipLaunchKernelGGL(k_ifft_y, dim3(200), dim3(256), 0, stream, G, out);
}